// Round 3
// baseline (467.452 us; speedup 1.0000x reference)
//
#include <hip/hip_runtime.h>
#include <stdint.h>

#define S_    4096
#define HID_  1024
#define H_    16
#define D_    64
#define N3    3072
#define SCALE_f 0.125f
#define NEG_f  (-1e30f)

typedef __attribute__((ext_vector_type(4))) float f32x4;
typedef __attribute__((ext_vector_type(8))) short bf16x8;

#define MFMA16(a,b,c) __builtin_amdgcn_mfma_f32_16x16x32_bf16((a),(b),(c),0,0,0)
#define GLDS16(g,l) __builtin_amdgcn_global_load_lds( \
    (__attribute__((address_space(1))) void*)(g), \
    (__attribute__((address_space(3))) void*)(l), 16, 0, 0)

__device__ __forceinline__ unsigned short f2b(float f){
  union { float f; uint32_t u; } a; a.f = f;
  uint32_t u = a.u;
  return (unsigned short)((u + 0x7fffu + ((u >> 16) & 1u)) >> 16);
}

// ---------------- cast x -> bf16 ----------------
__global__ __launch_bounds__(256) void cvt_x_kern(const float* __restrict__ x,
                                                  unsigned short* __restrict__ xb){
  int i = (blockIdx.x * 256 + threadIdx.x) * 4;
  const float4 v = *(const float4*)(x + i);
  ushort4 o;
  o.x = f2b(v.x); o.y = f2b(v.y); o.z = f2b(v.z); o.w = f2b(v.w);
  *(ushort4*)(xb + i) = o;
}

// ------------- transpose+cast W[k][n] -> wt[n][k] bf16 -------------
__global__ __launch_bounds__(256) void cvt_w_t_kern(const float* __restrict__ W,
                                                    unsigned short* __restrict__ wt,
                                                    int nbase){
  __shared__ float tile[32][33];
  int k0 = blockIdx.x * 32, n0 = blockIdx.y * 32;
  int tx = threadIdx.x, ty = threadIdx.y;   // 32 x 8
  for (int i = 0; i < 32; i += 8)
    tile[ty + i][tx] = W[(k0 + ty + i) * HID_ + n0 + tx];
  __syncthreads();
  for (int i = 0; i < 32; i += 8)
    wt[(nbase + n0 + ty + i) * HID_ + k0 + tx] = f2b(tile[tx][ty + i]);
}

// ------------- fused QKV GEMM: qkv[s][3072] = x @ [Wq|Wk|Wv] + bias (bf16 out) -------------
// m97 structure: 128x128 tile, BK=32, 4 waves (2x2), global_load_lds w=16.
#define BM 128
#define BN 128
#define BK 32
__global__ __launch_bounds__(256) void gemm_qkv_kern(
    const unsigned short* __restrict__ xb,   // [4096][1024] bf16
    const unsigned short* __restrict__ wt,   // [3072][1024] bf16 (W^T)
    const float* __restrict__ bq, const float* __restrict__ bk,
    const float* __restrict__ bv,
    unsigned short* __restrict__ qkv)        // [4096][3072] bf16
{
  __shared__ unsigned short As[BM * BK];   // [m][k]
  __shared__ unsigned short Bs[BN * BK];   // [n][k]
  int tid = threadIdx.x;
  int lane = tid & 63, wid = tid >> 6;
  int g = lane >> 4, l16 = lane & 15;
  int m0 = blockIdx.x * BM, n0 = blockIdx.y * BN;
  int wm = (wid >> 1) * 64, wn = (wid & 1) * 64;

  f32x4 acc[4][4];
  f32x4 z = {0.f, 0.f, 0.f, 0.f};
  for (int mi = 0; mi < 4; mi++) for (int ni = 0; ni < 4; ni++) acc[mi][ni] = z;

  for (int kt = 0; kt < HID_; kt += BK) {
    __syncthreads();
    for (int i = 0; i < 2; i++) {
      int flat = tid * 8 + i * 2048;          // elem in [128][32]
      int m = flat >> 5, k = flat & 31;
      GLDS16(xb + (m0 + m) * HID_ + kt + k, As + flat);
    }
    for (int i = 0; i < 2; i++) {
      int flat = tid * 8 + i * 2048;          // elem in [128][32]
      int n = flat >> 5, k = flat & 31;
      GLDS16(wt + (n0 + n) * HID_ + kt + k, Bs + flat);
    }
    __syncthreads();
    bf16x8 a[4], b[4];
    for (int mi = 0; mi < 4; mi++)
      a[mi] = *(const bf16x8*)(As + (wm + mi * 16 + l16) * BK + g * 8);
    for (int ni = 0; ni < 4; ni++)
      b[ni] = *(const bf16x8*)(Bs + (wn + ni * 16 + l16) * BK + g * 8);
    for (int mi = 0; mi < 4; mi++)
      for (int ni = 0; ni < 4; ni++)
        acc[mi][ni] = MFMA16(a[mi], b[ni], acc[mi][ni]);
  }

  for (int mi = 0; mi < 4; mi++)
    for (int ni = 0; ni < 4; ni++) {
      int col = n0 + wn + ni * 16 + l16;
      float bias = (col < 1024) ? bq[col] : ((col < 2048) ? bk[col - 1024] : bv[col - 2048]);
      for (int r = 0; r < 4; r++) {
        int row = m0 + wm + mi * 16 + g * 4 + r;
        qkv[row * N3 + col] = f2b(acc[mi][ni][r] + bias);
      }
    }
}

// ------------- flash attention: out[s][h*64+d] (f32) -------------
// block = (q-tile of 64, head). 4 waves x 16 q-rows. KV-tile = 64 keys.
#define PADR 72   // 64 + 8 bf16 pad: row stride 144 B (16B-aligned, conflict-light)
__global__ __launch_bounds__(256) void attn_kern(
    const unsigned short* __restrict__ qkv,  // [4096][3072] bf16
    const int* __restrict__ mask,            // [4096]
    float* __restrict__ out)                 // [4096][1024] f32
{
  __shared__ unsigned short Ks[64 * PADR];      // [key][d]
  __shared__ unsigned short Vt[64 * PADR];      // [d][key]
  __shared__ unsigned short Ps[4][16 * PADR];   // per-wave [qrow][key]

  int tid = threadIdx.x, lane = tid & 63, w = tid >> 6;
  int g = lane >> 4, l16 = lane & 15;
  int h = blockIdx.y;
  int q0 = blockIdx.x * 64;

  const unsigned short* Q = qkv + h * 64;
  const unsigned short* K = qkv + 1024 + h * 64;
  const unsigned short* V = qkv + 2048 + h * 64;

  // Q fragments in registers (wave w owns q-rows q0+w*16 .. +15)
  bf16x8 qf[2];
  for (int ks = 0; ks < 2; ks++)
    qf[ks] = *(const bf16x8*)(Q + (q0 + w * 16 + l16) * N3 + ks * 32 + g * 8);

  f32x4 po[4];
  f32x4 z = {0.f, 0.f, 0.f, 0.f};
  for (int nb = 0; nb < 4; nb++) po[nb] = z;
  float m_r[4], l_r[4];
  for (int r = 0; r < 4; r++) { m_r[r] = -__builtin_inff(); l_r[r] = 0.f; }

  for (int k0 = 0; k0 < S_; k0 += 64) {
    __syncthreads();
    // stage K tile [64][64] -> Ks (padded rows)
    for (int i = 0; i < 2; i++) {
      int flat = tid * 8 + i * 2048;
      int row = flat >> 6, d0 = flat & 63;
      *(bf16x8*)(&Ks[row * PADR + d0]) = *(const bf16x8*)(K + (k0 + row) * N3 + d0);
    }
    // stage V tile transposed -> Vt[d][key]
    for (int i = 0; i < 2; i++) {
      int flat = tid * 8 + i * 2048;
      int row = flat >> 6, d0 = flat & 63;
      bf16x8 v = *(const bf16x8*)(V + (k0 + row) * N3 + d0);
      for (int j = 0; j < 8; j++)
        Vt[(d0 + j) * PADR + row] = (unsigned short)v[j];
    }
    __syncthreads();

    // S = Q K^T  (16 q-rows x 64 keys per wave)
    f32x4 sc[4];
    for (int nb = 0; nb < 4; nb++) sc[nb] = z;
    for (int nb = 0; nb < 4; nb++)
      for (int ks = 0; ks < 2; ks++) {
        bf16x8 kf = *(const bf16x8*)(&Ks[(nb * 16 + l16) * PADR + ks * 32 + g * 8]);
        sc[nb] = MFMA16(qf[ks], kf, sc[nb]);
      }

    // scale + mask
    float pv[4][4];
    for (int nb = 0; nb < 4; nb++) {
      int mk = mask[k0 + nb * 16 + l16];
      for (int r = 0; r < 4; r++) {
        float s = sc[nb][r] * SCALE_f;
        pv[nb][r] = mk ? s : NEG_f;
      }
    }
    // online softmax per row (row = 4g + r, reduce across the 16-lane group)
    for (int r = 0; r < 4; r++) {
      float tmax = fmaxf(fmaxf(pv[0][r], pv[1][r]), fmaxf(pv[2][r], pv[3][r]));
      for (int off = 1; off < 16; off <<= 1) tmax = fmaxf(tmax, __shfl_xor(tmax, off, 64));
      float mnew = fmaxf(m_r[r], tmax);
      float alpha = __expf(m_r[r] - mnew);
      float rsum = 0.f;
      for (int nb = 0; nb < 4; nb++) {
        float p = __expf(pv[nb][r] - mnew);
        pv[nb][r] = p;
        rsum += p;
      }
      for (int off = 1; off < 16; off <<= 1) rsum += __shfl_xor(rsum, off, 64);
      l_r[r] = l_r[r] * alpha + rsum;
      m_r[r] = mnew;
      for (int nb = 0; nb < 4; nb++) po[nb][r] *= alpha;
    }
    // P -> LDS (C-layout -> A-layout relayout)
    for (int nb = 0; nb < 4; nb++)
      for (int r = 0; r < 4; r++)
        Ps[w][(g * 4 + r) * PADR + nb * 16 + l16] = f2b(pv[nb][r]);
    __syncthreads();
    // O += P V
    for (int ks = 0; ks < 2; ks++) {
      bf16x8 pf = *(const bf16x8*)(&Ps[w][l16 * PADR + ks * 32 + g * 8]);
      for (int nb = 0; nb < 4; nb++) {
        bf16x8 vf = *(const bf16x8*)(&Vt[(nb * 16 + l16) * PADR + ks * 32 + g * 8]);
        po[nb] = MFMA16(pf, vf, po[nb]);
      }
    }
  }

  for (int nb = 0; nb < 4; nb++)
    for (int r = 0; r < 4; r++) {
      int row = q0 + w * 16 + g * 4 + r;
      int col = h * 64 + nb * 16 + l16;
      out[row * HID_ + col] = po[nb][r] / l_r[r];
    }
}

extern "C" void kernel_launch(void* const* d_in, const int* in_sizes, int n_in,
                              void* d_out, int out_size, void* d_ws, size_t ws_size,
                              hipStream_t stream) {
  const float* x    = (const float*)d_in[0];
  const int*   mask = (const int*)d_in[1];
  const float* Wq   = (const float*)d_in[2];
  const float* bq   = (const float*)d_in[3];
  const float* Wk   = (const float*)d_in[4];
  const float* bk   = (const float*)d_in[5];
  const float* Wv   = (const float*)d_in[6];
  const float* bv   = (const float*)d_in[7];
  float* out = (float*)d_out;

  uint8_t* ws = (uint8_t*)d_ws;
  unsigned short* xb  = (unsigned short*)ws;                      // 8 MB  [4096][1024]
  unsigned short* wt  = (unsigned short*)(ws + (8u  << 20));      // 6 MB  [3072][1024]
  unsigned short* qkv = (unsigned short*)(ws + (14u << 20));      // 24 MB [4096][3072]

  cvt_x_kern<<<(S_ * HID_) / (256 * 4), 256, 0, stream>>>(x, xb);
  dim3 tg(HID_ / 32, HID_ / 32);
  cvt_w_t_kern<<<tg, dim3(32, 8), 0, stream>>>(Wq, wt, 0);
  cvt_w_t_kern<<<tg, dim3(32, 8), 0, stream>>>(Wk, wt, 1024);
  cvt_w_t_kern<<<tg, dim3(32, 8), 0, stream>>>(Wv, wt, 2048);
  gemm_qkv_kern<<<dim3(S_ / BM, N3 / BN), 256, 0, stream>>>(xb, wt, bq, bk, bv, qkv);
  attn_kern<<<dim3(S_ / 64, H_), 256, 0, stream>>>(qkv, mask, out);
}

// Round 7
// 364.207 us; speedup vs baseline: 1.2835x; 1.2835x over previous
//
#include <hip/hip_runtime.h>
#include <stdint.h>

#define S_    4096
#define HID_  1024
#define H_    16
#define N3    3072
#define NT    64
#define SCALE_f 0.125f
#define NEG_f  (-1e30f)

typedef __attribute__((ext_vector_type(4))) float f32x4;
typedef __attribute__((ext_vector_type(8))) short bf16x8;

#define MFMA16(a,b,c) __builtin_amdgcn_mfma_f32_16x16x32_bf16((a),(b),(c),0,0,0)
#define GLDS16(g,l) __builtin_amdgcn_global_load_lds( \
    (__attribute__((address_space(1))) void*)(g), \
    (__attribute__((address_space(3))) void*)(l), 16, 0, 0)

__device__ __forceinline__ unsigned short f2b(float f){
  union { float f; uint32_t u; } a; a.f = f;
  uint32_t u = a.u;
  return (unsigned short)((u + 0x7fffu + ((u >> 16) & 1u)) >> 16);
}

// ---------------- cast x -> bf16 ----------------
__global__ __launch_bounds__(256) void cvt_x_kern(const float* __restrict__ x,
                                                  unsigned short* __restrict__ xb){
  int i = (blockIdx.x * 256 + threadIdx.x) * 4;
  const float4 v = *(const float4*)(x + i);
  ushort4 o;
  o.x = f2b(v.x); o.y = f2b(v.y); o.z = f2b(v.z); o.w = f2b(v.w);
  *(ushort4*)(xb + i) = o;
}

// ------------- transpose+cast W[k][n] -> wt[n][k] bf16 -------------
__global__ __launch_bounds__(256) void cvt_w_t_kern(const float* __restrict__ W,
                                                    unsigned short* __restrict__ wt,
                                                    int nbase){
  __shared__ float tile[32][33];
  int k0 = blockIdx.x * 32, n0 = blockIdx.y * 32;
  int tx = threadIdx.x, ty = threadIdx.y;   // 32 x 8
  for (int i = 0; i < 32; i += 8)
    tile[ty + i][tx] = W[(k0 + ty + i) * HID_ + n0 + tx];
  __syncthreads();
  for (int i = 0; i < 32; i += 8)
    wt[(nbase + n0 + ty + i) * HID_ + k0 + tx] = f2b(tile[tx][ty + i]);
}

// ------------- fused QKV GEMM (m97 structure, unchanged) -------------
#define BM 128
#define BN 128
#define BK 32
__global__ __launch_bounds__(256) void gemm_qkv_kern(
    const unsigned short* __restrict__ xb,
    const unsigned short* __restrict__ wt,
    const float* __restrict__ bq, const float* __restrict__ bk,
    const float* __restrict__ bv,
    unsigned short* __restrict__ qkv)
{
  __shared__ unsigned short As[BM * BK];
  __shared__ unsigned short Bs[BN * BK];
  int tid = threadIdx.x;
  int lane = tid & 63, wid = tid >> 6;
  int g = lane >> 4, l16 = lane & 15;
  int m0 = blockIdx.x * BM, n0 = blockIdx.y * BN;
  int wm = (wid >> 1) * 64, wn = (wid & 1) * 64;

  f32x4 acc[4][4];
  f32x4 z = {0.f, 0.f, 0.f, 0.f};
  for (int mi = 0; mi < 4; mi++) for (int ni = 0; ni < 4; ni++) acc[mi][ni] = z;

  for (int kt = 0; kt < HID_; kt += BK) {
    __syncthreads();
    for (int i = 0; i < 2; i++) {
      int flat = tid * 8 + i * 2048;
      int m = flat >> 5, k = flat & 31;
      GLDS16(xb + (m0 + m) * HID_ + kt + k, As + flat);
    }
    for (int i = 0; i < 2; i++) {
      int flat = tid * 8 + i * 2048;
      int n = flat >> 5, k = flat & 31;
      GLDS16(wt + (n0 + n) * HID_ + kt + k, Bs + flat);
    }
    __syncthreads();
    bf16x8 a[4], b[4];
    for (int mi = 0; mi < 4; mi++)
      a[mi] = *(const bf16x8*)(As + (wm + mi * 16 + l16) * BK + g * 8);
    for (int ni = 0; ni < 4; ni++)
      b[ni] = *(const bf16x8*)(Bs + (wn + ni * 16 + l16) * BK + g * 8);
    for (int mi = 0; mi < 4; mi++)
      for (int ni = 0; ni < 4; ni++)
        acc[mi][ni] = MFMA16(a[mi], b[ni], acc[mi][ni]);
  }

  for (int mi = 0; mi < 4; mi++)
    for (int ni = 0; ni < 4; ni++) {
      int col = n0 + wn + ni * 16 + l16;
      float bias = (col < 1024) ? bq[col] : ((col < 2048) ? bk[col - 1024] : bv[col - 2048]);
      for (int r = 0; r < 4; r++) {
        int row = m0 + wm + mi * 16 + g * 4 + r;
        qkv[row * N3 + col] = f2b(acc[mi][ni][r] + bias);
      }
    }
}

// ------------- V transpose: qkv V region [s][h*64+d] -> vt[h][d][s] -------------
__global__ __launch_bounds__(256) void vt_kern(const unsigned short* __restrict__ qkv,
                                               unsigned short* __restrict__ vt){
  __shared__ unsigned short tl[64][72];
  int h = blockIdx.y, k0 = blockIdx.x * 64, tid = threadIdx.x;
  int key = tid >> 2, dq = (tid & 3) * 16;
  const unsigned short* src = qkv + (size_t)(k0 + key) * N3 + 2048 + h * 64 + dq;
  *(bf16x8*)&tl[key][dq]     = *(const bf16x8*)src;
  *(bf16x8*)&tl[key][dq + 8] = *(const bf16x8*)(src + 8);
  __syncthreads();
  int d = tid >> 2, kq = (tid & 3) * 16;
  unsigned short* dst = vt + ((size_t)h * 64 + d) * S_ + k0 + kq;
  bf16x8 o0, o1;
  for (int j = 0; j < 8; j++) { o0[j] = tl[kq + j][d]; o1[j] = tl[kq + 8 + j][d]; }
  *(bf16x8*)dst = o0; *(bf16x8*)(dst + 8) = o1;
}

// ------------- mask -> 64 bit-words -------------
__global__ void maskbits_kern(const int* __restrict__ mask,
                              unsigned long long* __restrict__ mb){
  int t = threadIdx.x;   // 64 threads
  unsigned long long wv = 0;
  for (int j = 0; j < 64; j++)
    wv |= (unsigned long long)(mask[t * 64 + j] != 0) << j;
  mb[t] = wv;
}

// ------------- flash attention, 2-phase dbuf + swizzled GLDS staging -------------
#define PADR 72
__global__ __launch_bounds__(256) void attn_kern(
    const unsigned short* __restrict__ qkv,
    const unsigned short* __restrict__ vt,     // [16][64][4096]
    const unsigned long long* __restrict__ mb, // [64]
    float* __restrict__ out)
{
  __shared__ unsigned short Ks[2][64 * 64];   // swizzled: LDS[row*64 + ((byte^((row&7)<<4))>>1)]
  __shared__ unsigned short Vs[2][64 * 64];
  __shared__ unsigned short Ps[4][16 * PADR];
  __shared__ unsigned long long MaskL[NT];

  int tid = threadIdx.x, lane = tid & 63, w = tid >> 6;
  int g = lane >> 4, l16 = lane & 15;
  // XCD swizzle: grid 1024 = 8 XCD x 128; heads 2k,2k+1 resident on XCD k's L2
  int bid = blockIdx.x;
  int swz = (bid & 7) * 128 + (bid >> 3);
  int h = swz >> 6, q0 = (swz & 63) * 64;

  const unsigned short* Q = qkv + h * 64;
  const unsigned short* K = qkv + 1024 + h * 64;
  const unsigned short* V = vt + (size_t)h * 64 * S_;   // rows = d, row-stride S_

  if (tid < NT) MaskL[tid] = mb[tid];

  bf16x8 qf[2];
  for (int ks = 0; ks < 2; ks++)
    qf[ks] = *(const bf16x8*)(Q + (size_t)(q0 + w * 16 + l16) * N3 + ks * 32 + g * 8);

  f32x4 po[4];
  f32x4 z = {0.f, 0.f, 0.f, 0.f};
  for (int nb = 0; nb < 4; nb++) po[nb] = z;
  float m_r[4], l_r[4];
  for (int r = 0; r < 4; r++) { m_r[r] = -__builtin_inff(); l_r[r] = 0.f; }

  // read-side swizzle constants: row = nb*16+l16 -> row&7 == l16&7
  int swl = (l16 & 7) << 4;
  int rof[2];
  for (int ks = 0; ks < 2; ks++) rof[ks] = ((ks * 64 + g * 16) ^ swl) >> 1;

  // STAGE: linear GLDS dest, inverse-swizzled global source (rule #21)
  auto STAGE = [&](int b, int t) {
    int k0 = t * 64;
    for (int i = 0; i < 2; i++) {
      int F = tid * 16 + i * 4096;          // dest byte in [64][128B]
      int row = F >> 7, inner = F & 127;
      int sin = (inner ^ ((row & 7) << 4)) >> 1;   // shorts
      GLDS16(K + (size_t)(k0 + row) * N3 + sin, &Ks[b][F >> 1]);
      GLDS16(V + (size_t)row * S_ + k0 + sin,    &Vs[b][F >> 1]);
    }
  };

  STAGE(0, 0);
  asm volatile("s_waitcnt vmcnt(0) lgkmcnt(0)" ::: "memory");
  __builtin_amdgcn_s_barrier();

  int cur = 0;
  for (int t = 0; t < NT; t++) {
    if (t + 1 < NT) STAGE(cur ^ 1, t + 1);     // issue next-tile loads early
    unsigned long long mw = MaskL[t];

    // S = Q K^T
    f32x4 sc[4];
    for (int nb = 0; nb < 4; nb++) sc[nb] = z;
    for (int nb = 0; nb < 4; nb++) {
      int rb = (nb * 16 + l16) * 64;
      for (int ks = 0; ks < 2; ks++) {
        bf16x8 kf = *(const bf16x8*)(&Ks[cur][rb + rof[ks]]);
        sc[nb] = MFMA16(qf[ks], kf, sc[nb]);
      }
    }

    // scale + mask (bitmask, no global loads)
    float pvv[4][4];
    for (int nb = 0; nb < 4; nb++) {
      int on = ((mw >> (nb * 16 + l16)) & 1ull) != 0;
      for (int r = 0; r < 4; r++) {
        float s = sc[nb][r] * SCALE_f;
        pvv[nb][r] = on ? s : NEG_f;
      }
    }
    // online softmax (16-lane-group reduce; row = g*4+r)
    for (int r = 0; r < 4; r++) {
      float tmax = fmaxf(fmaxf(pvv[0][r], pvv[1][r]), fmaxf(pvv[2][r], pvv[3][r]));
      for (int off = 1; off < 16; off <<= 1) tmax = fmaxf(tmax, __shfl_xor(tmax, off, 64));
      float mnew = fmaxf(m_r[r], tmax);
      float alpha = __expf(m_r[r] - mnew);
      float rsum = 0.f;
      for (int nb = 0; nb < 4; nb++) {
        float p = __expf(pvv[nb][r] - mnew);
        pvv[nb][r] = p; rsum += p;
      }
      for (int off = 1; off < 16; off <<= 1) rsum += __shfl_xor(rsum, off, 64);
      l_r[r] = l_r[r] * alpha + rsum;
      m_r[r] = mnew;
      for (int nb = 0; nb < 4; nb++) po[nb][r] *= alpha;
    }
    // P relayout via per-wave LDS (no barrier needed: same-wave DS ops are ordered)
    for (int nb = 0; nb < 4; nb++)
      for (int r = 0; r < 4; r++)
        Ps[w][(g * 4 + r) * PADR + nb * 16 + l16] = f2b(pvv[nb][r]);

    // O += P V
    for (int ks = 0; ks < 2; ks++) {
      bf16x8 pf = *(const bf16x8*)(&Ps[w][l16 * PADR + ks * 32 + g * 8]);
      for (int nb = 0; nb < 4; nb++) {
        bf16x8 vf = *(const bf16x8*)(&Vs[cur][(nb * 16 + l16) * 64 + rof[ks]]);
        po[nb] = MFMA16(pf, vf, po[nb]);
      }
    }

    asm volatile("s_waitcnt vmcnt(0) lgkmcnt(0)" ::: "memory");
    __builtin_amdgcn_s_barrier();
    cur ^= 1;
  }

  for (int nb = 0; nb < 4; nb++)
    for (int r = 0; r < 4; r++) {
      int row = q0 + w * 16 + g * 4 + r;
      int col = h * 64 + nb * 16 + l16;
      out[(size_t)row * HID_ + col] = po[nb][r] / l_r[r];
    }
}

extern "C" void kernel_launch(void* const* d_in, const int* in_sizes, int n_in,
                              void* d_out, int out_size, void* d_ws, size_t ws_size,
                              hipStream_t stream) {
  const float* x    = (const float*)d_in[0];
  const int*   mask = (const int*)d_in[1];
  const float* Wq   = (const float*)d_in[2];
  const float* bq   = (const float*)d_in[3];
  const float* Wk   = (const float*)d_in[4];
  const float* bk   = (const float*)d_in[5];
  const float* Wv   = (const float*)d_in[6];
  const float* bv   = (const float*)d_in[7];
  float* out = (float*)d_out;

  uint8_t* ws = (uint8_t*)d_ws;
  unsigned short* xb  = (unsigned short*)ws;                      // 8 MB (dead after GEMM)
  unsigned short* wt  = (unsigned short*)(ws + (8u  << 20));      // 6 MB (dead after GEMM)
  unsigned short* qkv = (unsigned short*)(ws + (14u << 20));      // 24 MB
  unsigned short* vt  = (unsigned short*)ws;                      // reuse xb slot: 8 MB
  unsigned long long* mb = (unsigned long long*)(ws + (8u << 20)); // reuse wt slot: 512 B

  cvt_x_kern<<<(S_ * HID_) / (256 * 4), 256, 0, stream>>>(x, xb);
  dim3 tg(HID_ / 32, HID_ / 32);
  cvt_w_t_kern<<<tg, dim3(32, 8), 0, stream>>>(Wq, wt, 0);
  cvt_w_t_kern<<<tg, dim3(32, 8), 0, stream>>>(Wk, wt, 1024);
  cvt_w_t_kern<<<tg, dim3(32, 8), 0, stream>>>(Wv, wt, 2048);
  gemm_qkv_kern<<<dim3(S_ / BM, N3 / BN), 256, 0, stream>>>(xb, wt, bq, bk, bv, qkv);
  vt_kern<<<dim3(S_ / 64, H_), 256, 0, stream>>>(qkv, vt);        // overwrites xb (dead)
  maskbits_kern<<<1, 64, 0, stream>>>(mask, mb);                  // overwrites wt (dead)
  attn_kern<<<S_ / 64 * H_, 256, 0, stream>>>(qkv, vt, mb, out);
}

// Round 10
// 271.487 us; speedup vs baseline: 1.7218x; 1.3415x over previous
//
#include <hip/hip_runtime.h>
#include <stdint.h>

#define S_    4096
#define HID_  1024
#define H_    16
#define N3    3072
#define NT    64
#define SCALE_f 0.125f
#define NEG_f  (-1e30f)
#define SCL2  (0.125f * 1.44269504089f)   // SCALE * log2(e)

typedef __attribute__((ext_vector_type(4))) float f32x4;
typedef __attribute__((ext_vector_type(8))) short bf16x8;
typedef __attribute__((ext_vector_type(4))) short bf16x4;

#define MFMA16(a,b,c) __builtin_amdgcn_mfma_f32_16x16x32_bf16((a),(b),(c),0,0,0)
#define GLDS16(g,l) __builtin_amdgcn_global_load_lds( \
    (__attribute__((address_space(1))) void*)(g), \
    (__attribute__((address_space(3))) void*)(l), 16, 0, 0)

__device__ __forceinline__ f32x4 MFMA16K16(bf16x4 a, bf16x4 b, f32x4 c){
#if __has_builtin(__builtin_amdgcn_mfma_f32_16x16x16bf16_1k)
  return __builtin_amdgcn_mfma_f32_16x16x16bf16_1k(a, b, c, 0, 0, 0);
#else
  asm volatile("v_mfma_f32_16x16x16_bf16 %0, %1, %2, %0" : "+v"(c) : "v"(a), "v"(b));
  return c;
#endif
}

__device__ __forceinline__ unsigned short f2b(float f){
  union { float f; uint32_t u; } a; a.f = f;
  uint32_t u = a.u;
  return (unsigned short)((u + 0x7fffu + ((u >> 16) & 1u)) >> 16);
}

// ---------------- cast x -> bf16 ----------------
__global__ __launch_bounds__(256) void cvt_x_kern(const float* __restrict__ x,
                                                  unsigned short* __restrict__ xb){
  int i = (blockIdx.x * 256 + threadIdx.x) * 4;
  const float4 v = *(const float4*)(x + i);
  ushort4 o;
  o.x = f2b(v.x); o.y = f2b(v.y); o.z = f2b(v.z); o.w = f2b(v.w);
  *(ushort4*)(xb + i) = o;
}

// ------------- transpose+cast W[k][n] -> wt[n][k] bf16 -------------
__global__ __launch_bounds__(256) void cvt_w_t_kern(const float* __restrict__ W,
                                                    unsigned short* __restrict__ wt,
                                                    int nbase){
  __shared__ float tile[32][33];
  int k0 = blockIdx.x * 32, n0 = blockIdx.y * 32;
  int tx = threadIdx.x, ty = threadIdx.y;   // 32 x 8
  for (int i = 0; i < 32; i += 8)
    tile[ty + i][tx] = W[(k0 + ty + i) * HID_ + n0 + tx];
  __syncthreads();
  for (int i = 0; i < 32; i += 8)
    wt[(nbase + n0 + ty + i) * HID_ + k0 + tx] = f2b(tile[tx][ty + i]);
}

// ------------- fused QKV GEMM (m97 structure, unchanged) -------------
#define BM 128
#define BN 128
#define BK 32
__global__ __launch_bounds__(256) void gemm_qkv_kern(
    const unsigned short* __restrict__ xb,
    const unsigned short* __restrict__ wt,
    const float* __restrict__ bq, const float* __restrict__ bk,
    const float* __restrict__ bv,
    unsigned short* __restrict__ qkv)
{
  __shared__ unsigned short As[BM * BK];
  __shared__ unsigned short Bs[BN * BK];
  int tid = threadIdx.x;
  int lane = tid & 63, wid = tid >> 6;
  int g = lane >> 4, l16 = lane & 15;
  int m0 = blockIdx.x * BM, n0 = blockIdx.y * BN;
  int wm = (wid >> 1) * 64, wn = (wid & 1) * 64;

  f32x4 acc[4][4];
  f32x4 z = {0.f, 0.f, 0.f, 0.f};
  for (int mi = 0; mi < 4; mi++) for (int ni = 0; ni < 4; ni++) acc[mi][ni] = z;

  for (int kt = 0; kt < HID_; kt += BK) {
    __syncthreads();
    for (int i = 0; i < 2; i++) {
      int flat = tid * 8 + i * 2048;
      int m = flat >> 5, k = flat & 31;
      GLDS16(xb + (m0 + m) * HID_ + kt + k, As + flat);
    }
    for (int i = 0; i < 2; i++) {
      int flat = tid * 8 + i * 2048;
      int n = flat >> 5, k = flat & 31;
      GLDS16(wt + (n0 + n) * HID_ + kt + k, Bs + flat);
    }
    __syncthreads();
    bf16x8 a[4], b[4];
    for (int mi = 0; mi < 4; mi++)
      a[mi] = *(const bf16x8*)(As + (wm + mi * 16 + l16) * BK + g * 8);
    for (int ni = 0; ni < 4; ni++)
      b[ni] = *(const bf16x8*)(Bs + (wn + ni * 16 + l16) * BK + g * 8);
    for (int mi = 0; mi < 4; mi++)
      for (int ni = 0; ni < 4; ni++)
        acc[mi][ni] = MFMA16(a[mi], b[ni], acc[mi][ni]);
  }

  for (int mi = 0; mi < 4; mi++)
    for (int ni = 0; ni < 4; ni++) {
      int col = n0 + wn + ni * 16 + l16;
      float bias = (col < 1024) ? bq[col] : ((col < 2048) ? bk[col - 1024] : bv[col - 2048]);
      for (int r = 0; r < 4; r++) {
        int row = m0 + wm + mi * 16 + g * 4 + r;
        qkv[row * N3 + col] = f2b(acc[mi][ni][r] + bias);
      }
    }
}

// ------------- V transpose: qkv V region [s][h*64+d] -> vt[h][d][s] -------------
__global__ __launch_bounds__(256) void vt_kern(const unsigned short* __restrict__ qkv,
                                               unsigned short* __restrict__ vt){
  __shared__ unsigned short tl[64][72];
  int h = blockIdx.y, k0 = blockIdx.x * 64, tid = threadIdx.x;
  int key = tid >> 2, dq = (tid & 3) * 16;
  const unsigned short* src = qkv + (size_t)(k0 + key) * N3 + 2048 + h * 64 + dq;
  *(bf16x8*)&tl[key][dq]     = *(const bf16x8*)src;
  *(bf16x8*)&tl[key][dq + 8] = *(const bf16x8*)(src + 8);
  __syncthreads();
  int d = tid >> 2, kq = (tid & 3) * 16;
  unsigned short* dst = vt + ((size_t)h * 64 + d) * S_ + k0 + kq;
  bf16x8 o0, o1;
  for (int j = 0; j < 8; j++) { o0[j] = tl[kq + j][d]; o1[j] = tl[kq + 8 + j][d]; }
  *(bf16x8*)dst = o0; *(bf16x8*)(dst + 8) = o1;
}

// ------------- mask -> 64 bit-words -------------
__global__ void maskbits_kern(const int* __restrict__ mask,
                              unsigned long long* __restrict__ mb){
  int t = threadIdx.x;   // 64 threads
  unsigned long long wv = 0;
  for (int j = 0; j < 64; j++)
    wv |= (unsigned long long)(mask[t * 64 + j] != 0) << j;
  mb[t] = wv;
}

// ------------- flash attention, swapped-QK^T (lane-owns-q-row), P in-register -------------
__global__ __launch_bounds__(256, 4) void attn_kern(
    const unsigned short* __restrict__ qkv,
    const unsigned short* __restrict__ vt,     // [16][64][4096]
    const unsigned long long* __restrict__ mb, // [64]
    float* __restrict__ out)
{
  __shared__ unsigned short Ks[2][64 * 64];   // [key][dim], XOR-swizzled
  __shared__ unsigned short Vs[2][64 * 64];   // [d][key],  XOR-swizzled
  __shared__ unsigned long long MaskL[NT];

  int tid = threadIdx.x, lane = tid & 63, w = tid >> 6;
  int g = lane >> 4, l16 = lane & 15;
  int bid = blockIdx.x;
  int swz = (bid & 7) * 128 + (bid >> 3);     // XCD swizzle (1024 = 8 x 128, bijective)
  int h = swz >> 6, q0 = (swz & 63) * 64;

  const unsigned short* Q = qkv + h * 64;
  const unsigned short* K = qkv + 1024 + h * 64;
  const unsigned short* V = vt + (size_t)h * 64 * S_;

  if (tid < NT) MaskL[tid] = mb[tid];

  // Q fragment: lane (g,l16) -> Q[q0+w*16+l16][ks*32 + g*8 ..+7]  (B-operand of QK^T)
  bf16x8 qf[2];
  for (int ks = 0; ks < 2; ks++)
    qf[ks] = *(const bf16x8*)(Q + (size_t)(q0 + w * 16 + l16) * N3 + ks * 32 + g * 8);

  f32x4 po[4];                                // O^T[col=q=l16][row=d=g*4+r], db-tiled
  f32x4 z = {0.f, 0.f, 0.f, 0.f};
  for (int db = 0; db < 4; db++) po[db] = z;
  float m_l = -__builtin_inff(), l_l = 0.f;   // per-lane: q = q0+w*16+l16 (log2 domain)

  int swl = (l16 & 7) << 4;                   // read-side XOR (row&7 == l16&7 for all reads)
  int rof[2];                                 // K-read: b128 at dim-slice ks*32+g*8 shorts
  for (int ks = 0; ks < 2; ks++) rof[ks] = ((ks * 64 + g * 16) ^ swl) >> 1;
  int vof[4];                                 // V-read: b64 at key-slice nb*16+g*4 shorts
  for (int nb = 0; nb < 4; nb++) vof[nb] = ((nb * 32 + g * 8) ^ swl) >> 1;

  auto STAGE = [&](int b, int t) {
    int k0 = t * 64;
    for (int i = 0; i < 2; i++) {
      int F = tid * 16 + i * 4096;            // dest byte in [64][128B], linear
      int row = F >> 7, inner = F & 127;
      int sin = (inner ^ ((row & 7) << 4)) >> 1;
      GLDS16(K + (size_t)(k0 + row) * N3 + sin, &Ks[b][F >> 1]);
      GLDS16(V + (size_t)row * S_ + k0 + sin,    &Vs[b][F >> 1]);
    }
  };

  STAGE(0, 0);
  asm volatile("s_waitcnt vmcnt(0) lgkmcnt(0)" ::: "memory");
  __builtin_amdgcn_s_barrier();

  int cur = 0;
  for (int t = 0; t < NT; t++) {
    if (t + 1 < NT) STAGE(cur ^ 1, t + 1);
    unsigned long long mw = MaskL[t];

    // S^T = K Q^T : C[col=q=l16][row=key=nb*16+g*4+r]
    f32x4 sc[4];
    for (int nb = 0; nb < 4; nb++) sc[nb] = z;
    for (int nb = 0; nb < 4; nb++) {
      int rb = (nb * 16 + l16) * 64;
      for (int ks = 0; ks < 2; ks++) {
        bf16x8 kf = *(const bf16x8*)(&Ks[cur][rb + rof[ks]]);
        sc[nb] = MFMA16(kf, qf[ks], sc[nb]);
      }
    }

    // scale (log2 domain) + mask; lane owns one q-row, 16 keys at nb*16+g*4+r
    float pl[4][4];
    for (int nb = 0; nb < 4; nb++) {
      unsigned mn = (unsigned)((mw >> (nb * 16 + g * 4)) & 0xFull);
      for (int r = 0; r < 4; r++)
        pl[nb][r] = ((mn >> r) & 1u) ? sc[nb][r] * SCL2 : NEG_f;
    }

    // row max: in-lane 16 + 2 shfls across g-groups
    float pmax = pl[0][0];
    for (int nb = 0; nb < 4; nb++)
      for (int r = 0; r < 4; r++) pmax = fmaxf(pmax, pl[nb][r]);
    pmax = fmaxf(pmax, __shfl_xor(pmax, 16, 64));
    pmax = fmaxf(pmax, __shfl_xor(pmax, 32, 64));

    // defer-max (T13, THR=8 in log2 domain -> P bounded by 256)
    if (__ballot(pmax > m_l + 8.f)) {
      float mnew = fmaxf(m_l, pmax);
      float alpha = __builtin_amdgcn_exp2f(m_l - mnew);
      for (int db = 0; db < 4; db++) po[db] *= alpha;
      l_l *= alpha;
      m_l = mnew;
    }

    // P = 2^(s - m), pack to bf16x4 per nb (feeds PV B-operand directly, no LDS)
    float rsum = 0.f;
    bf16x4 pb[4];
    for (int nb = 0; nb < 4; nb++)
      for (int r = 0; r < 4; r++) {
        float p = __builtin_amdgcn_exp2f(pl[nb][r] - m_l);
        rsum += p;
        pb[nb][r] = (short)f2b(p);
      }
    rsum += __shfl_xor(rsum, 16, 64);
    rsum += __shfl_xor(rsum, 32, 64);
    l_l += rsum;

    // O^T += V^T P^T : A = Vs[d][key] b64 frags, B = pb (in-register)
    for (int db = 0; db < 4; db++) {
      int rb = (db * 16 + l16) * 64;
      for (int nb = 0; nb < 4; nb++) {
        bf16x4 va = *(const bf16x4*)(&Vs[cur][rb + vof[nb]]);
        po[db] = MFMA16K16(va, pb[nb], po[db]);
      }
    }

    asm volatile("s_waitcnt vmcnt(0) lgkmcnt(0)" ::: "memory");
    __builtin_amdgcn_s_barrier();
    cur ^= 1;
  }

  float inv = 1.0f / l_l;
  int q = q0 + w * 16 + l16;
  for (int db = 0; db < 4; db++) {
    f32x4 v = po[db] * inv;
    *(f32x4*)(out + (size_t)q * HID_ + h * 64 + db * 16 + g * 4) = v;
  }
}

extern "C" void kernel_launch(void* const* d_in, const int* in_sizes, int n_in,
                              void* d_out, int out_size, void* d_ws, size_t ws_size,
                              hipStream_t stream) {
  const float* x    = (const float*)d_in[0];
  const int*   mask = (const int*)d_in[1];
  const float* Wq   = (const float*)d_in[2];
  const float* bq   = (const float*)d_in[3];
  const float* Wk   = (const float*)d_in[4];
  const float* bk   = (const float*)d_in[5];
  const float* Wv   = (const float*)d_in[6];
  const float* bv   = (const float*)d_in[7];
  float* out = (float*)d_out;

  uint8_t* ws = (uint8_t*)d_ws;
  unsigned short* xb  = (unsigned short*)ws;                      // 8 MB (dead after GEMM)
  unsigned short* wt  = (unsigned short*)(ws + (8u  << 20));      // 6 MB (dead after GEMM)
  unsigned short* qkv = (unsigned short*)(ws + (14u << 20));      // 24 MB
  unsigned short* vt  = (unsigned short*)ws;                      // reuse xb slot: 8 MB
  unsigned long long* mb = (unsigned long long*)(ws + (8u << 20)); // reuse wt slot: 512 B

  cvt_x_kern<<<(S_ * HID_) / (256 * 4), 256, 0, stream>>>(x, xb);
  dim3 tg(HID_ / 32, HID_ / 32);
  cvt_w_t_kern<<<tg, dim3(32, 8), 0, stream>>>(Wq, wt, 0);
  cvt_w_t_kern<<<tg, dim3(32, 8), 0, stream>>>(Wk, wt, 1024);
  cvt_w_t_kern<<<tg, dim3(32, 8), 0, stream>>>(Wv, wt, 2048);
  gemm_qkv_kern<<<dim3(S_ / BM, N3 / BN), 256, 0, stream>>>(xb, wt, bq, bk, bv, qkv);
  vt_kern<<<dim3(S_ / 64, H_), 256, 0, stream>>>(qkv, vt);        // overwrites xb (dead)
  maskbits_kern<<<1, 64, 0, stream>>>(mask, mb);                  // overwrites wt (dead)
  attn_kern<<<S_ / 64 * H_, 256, 0, stream>>>(qkv, vt, mb, out);
}

// Round 11
// 261.761 us; speedup vs baseline: 1.7858x; 1.0372x over previous
//
#include <hip/hip_runtime.h>
#include <stdint.h>

#define S_    4096
#define HID_  1024
#define H_    16
#define N3    3072
#define NT    64
#define SCALE_f 0.125f
#define NEG_f  (-1e30f)
#define SCL2  (0.125f * 1.44269504089f)   // SCALE * log2(e)
#define THRRAW 44.3614f                   // 8 log2-units in raw-score domain

typedef __attribute__((ext_vector_type(4))) float f32x4;
typedef __attribute__((ext_vector_type(8))) short bf16x8;
typedef __attribute__((ext_vector_type(4))) short bf16x4;

#define MFMA16(a,b,c) __builtin_amdgcn_mfma_f32_16x16x32_bf16((a),(b),(c),0,0,0)
#define GLDS16(g,l) __builtin_amdgcn_global_load_lds( \
    (__attribute__((address_space(1))) void*)(g), \
    (__attribute__((address_space(3))) void*)(l), 16, 0, 0)

__device__ __forceinline__ f32x4 MFMA16K16(bf16x4 a, bf16x4 b, f32x4 c){
#if __has_builtin(__builtin_amdgcn_mfma_f32_16x16x16bf16_1k)
  return __builtin_amdgcn_mfma_f32_16x16x16bf16_1k(a, b, c, 0, 0, 0);
#else
  asm volatile("v_mfma_f32_16x16x16_bf16 %0, %1, %2, %0" : "+v"(c) : "v"(a), "v"(b));
  return c;
#endif
}

__device__ __forceinline__ float max3f(float a, float b, float c){
  float d; asm("v_max3_f32 %0, %1, %2, %3" : "=v"(d) : "v"(a), "v"(b), "v"(c)); return d;
}
__device__ __forceinline__ uint32_t cvtpk(float lo, float hi){
  uint32_t r; asm("v_cvt_pk_bf16_f32 %0, %1, %2" : "=v"(r) : "v"(lo), "v"(hi)); return r;
}

__device__ __forceinline__ unsigned short f2b(float f){
  union { float f; uint32_t u; } a; a.f = f;
  uint32_t u = a.u;
  return (unsigned short)((u + 0x7fffu + ((u >> 16) & 1u)) >> 16);
}

// ---------------- cast x -> bf16 ----------------
__global__ __launch_bounds__(256) void cvt_x_kern(const float* __restrict__ x,
                                                  unsigned short* __restrict__ xb){
  int i = (blockIdx.x * 256 + threadIdx.x) * 4;
  const float4 v = *(const float4*)(x + i);
  ushort4 o;
  o.x = f2b(v.x); o.y = f2b(v.y); o.z = f2b(v.z); o.w = f2b(v.w);
  *(ushort4*)(xb + i) = o;
}

// ------------- transpose+cast W[k][n] -> wt[n][k] bf16 -------------
__global__ __launch_bounds__(256) void cvt_w_t_kern(const float* __restrict__ W,
                                                    unsigned short* __restrict__ wt,
                                                    int nbase){
  __shared__ float tile[32][33];
  int k0 = blockIdx.x * 32, n0 = blockIdx.y * 32;
  int tx = threadIdx.x, ty = threadIdx.y;   // 32 x 8
  for (int i = 0; i < 32; i += 8)
    tile[ty + i][tx] = W[(k0 + ty + i) * HID_ + n0 + tx];
  __syncthreads();
  for (int i = 0; i < 32; i += 8)
    wt[(nbase + n0 + ty + i) * HID_ + k0 + tx] = f2b(tile[tx][ty + i]);
}

// ------------- fused QKV GEMM (m97 structure, unchanged) -------------
#define BM 128
#define BN 128
#define BK 32
__global__ __launch_bounds__(256) void gemm_qkv_kern(
    const unsigned short* __restrict__ xb,
    const unsigned short* __restrict__ wt,
    const float* __restrict__ bq, const float* __restrict__ bk,
    const float* __restrict__ bv,
    unsigned short* __restrict__ qkv)
{
  __shared__ unsigned short As[BM * BK];
  __shared__ unsigned short Bs[BN * BK];
  int tid = threadIdx.x;
  int lane = tid & 63, wid = tid >> 6;
  int g = lane >> 4, l16 = lane & 15;
  int m0 = blockIdx.x * BM, n0 = blockIdx.y * BN;
  int wm = (wid >> 1) * 64, wn = (wid & 1) * 64;

  f32x4 acc[4][4];
  f32x4 z = {0.f, 0.f, 0.f, 0.f};
  for (int mi = 0; mi < 4; mi++) for (int ni = 0; ni < 4; ni++) acc[mi][ni] = z;

  for (int kt = 0; kt < HID_; kt += BK) {
    __syncthreads();
    for (int i = 0; i < 2; i++) {
      int flat = tid * 8 + i * 2048;
      int m = flat >> 5, k = flat & 31;
      GLDS16(xb + (m0 + m) * HID_ + kt + k, As + flat);
    }
    for (int i = 0; i < 2; i++) {
      int flat = tid * 8 + i * 2048;
      int n = flat >> 5, k = flat & 31;
      GLDS16(wt + (n0 + n) * HID_ + kt + k, Bs + flat);
    }
    __syncthreads();
    bf16x8 a[4], b[4];
    for (int mi = 0; mi < 4; mi++)
      a[mi] = *(const bf16x8*)(As + (wm + mi * 16 + l16) * BK + g * 8);
    for (int ni = 0; ni < 4; ni++)
      b[ni] = *(const bf16x8*)(Bs + (wn + ni * 16 + l16) * BK + g * 8);
    for (int mi = 0; mi < 4; mi++)
      for (int ni = 0; ni < 4; ni++)
        acc[mi][ni] = MFMA16(a[mi], b[ni], acc[mi][ni]);
  }

  for (int mi = 0; mi < 4; mi++)
    for (int ni = 0; ni < 4; ni++) {
      int col = n0 + wn + ni * 16 + l16;
      float bias = (col < 1024) ? bq[col] : ((col < 2048) ? bk[col - 1024] : bv[col - 2048]);
      for (int r = 0; r < 4; r++) {
        int row = m0 + wm + mi * 16 + g * 4 + r;
        qkv[row * N3 + col] = f2b(acc[mi][ni][r] + bias);
      }
    }
}

// ------------- V transpose + mask-zeroing: [s][h*64+d] -> vt[h][d][s]; masked keys -> 0 -------------
__global__ __launch_bounds__(256) void vt_kern(const unsigned short* __restrict__ qkv,
                                               const int* __restrict__ mask,
                                               unsigned short* __restrict__ vt){
  __shared__ unsigned short tl[64][72];
  int h = blockIdx.y, k0 = blockIdx.x * 64, tid = threadIdx.x;
  int key = tid >> 2, dq = (tid & 3) * 16;
  const unsigned short* src = qkv + (size_t)(k0 + key) * N3 + 2048 + h * 64 + dq;
  bf16x8 v0 = *(const bf16x8*)src;
  bf16x8 v1 = *(const bf16x8*)(src + 8);
  if (mask[k0 + key] == 0) {            // zero masked V rows: PV then needs no mask
    bf16x8 zz = {0,0,0,0,0,0,0,0};
    v0 = zz; v1 = zz;
  }
  *(bf16x8*)&tl[key][dq]     = v0;
  *(bf16x8*)&tl[key][dq + 8] = v1;
  __syncthreads();
  int d = tid >> 2, kq = (tid & 3) * 16;
  unsigned short* dst = vt + ((size_t)h * 64 + d) * S_ + k0 + kq;
  bf16x8 o0, o1;
  for (int j = 0; j < 8; j++) { o0[j] = tl[kq + j][d]; o1[j] = tl[kq + 8 + j][d]; }
  *(bf16x8*)dst = o0; *(bf16x8*)(dst + 8) = o1;
}

// ------------- mask -> 64 bit-words -------------
__global__ void maskbits_kern(const int* __restrict__ mask,
                              unsigned long long* __restrict__ mb){
  int t = threadIdx.x;   // 64 threads
  unsigned long long wv = 0;
  for (int j = 0; j < 64; j++)
    wv |= (unsigned long long)(mask[t * 64 + j] != 0) << j;
  mb[t] = wv;
}

// ------------- flash attention, swapped-QK^T, VALU-diet softmax -------------
__global__ __launch_bounds__(256, 4) void attn_kern(
    const unsigned short* __restrict__ qkv,
    const unsigned short* __restrict__ vt,     // [16][64][4096], masked rows zeroed
    const unsigned long long* __restrict__ mb, // [64]
    float* __restrict__ out)
{
  __shared__ unsigned short Ks[2][64 * 64];   // [key][dim], XOR-swizzled
  __shared__ unsigned short Vs[2][64 * 64];   // [d][key],  XOR-swizzled
  __shared__ unsigned long long MaskL[NT];

  int tid = threadIdx.x, lane = tid & 63, w = tid >> 6;
  int g = lane >> 4, l16 = lane & 15;
  int bid = blockIdx.x;
  int swz = (bid & 7) * 128 + (bid >> 3);     // XCD swizzle (1024 = 8 x 128, bijective)
  int h = swz >> 6, q0 = (swz & 63) * 64;

  const unsigned short* Q = qkv + h * 64;
  const unsigned short* K = qkv + 1024 + h * 64;
  const unsigned short* V = vt + (size_t)h * 64 * S_;

  if (tid < NT) MaskL[tid] = mb[tid];

  bf16x8 qf[2];
  for (int ks = 0; ks < 2; ks++)
    qf[ks] = *(const bf16x8*)(Q + (size_t)(q0 + w * 16 + l16) * N3 + ks * 32 + g * 8);

  f32x4 po[4];                                // O^T[col=q=l16][row=d=g*4+r]
  f32x4 z = {0.f, 0.f, 0.f, 0.f};
  for (int db = 0; db < 4; db++) po[db] = z;
  float m_l = -__builtin_inff(), l_l = 0.f;   // m in RAW score units

  int swl = (l16 & 7) << 4;
  int rof[2];
  for (int ks = 0; ks < 2; ks++) rof[ks] = ((ks * 64 + g * 16) ^ swl) >> 1;
  int vof[4];
  for (int nb = 0; nb < 4; nb++) vof[nb] = ((nb * 32 + g * 8) ^ swl) >> 1;

  auto STAGE = [&](int b, int t) {
    int k0 = t * 64;
    for (int i = 0; i < 2; i++) {
      int F = tid * 16 + i * 4096;
      int row = F >> 7, inner = F & 127;
      int sin = (inner ^ ((row & 7) << 4)) >> 1;
      GLDS16(K + (size_t)(k0 + row) * N3 + sin, &Ks[b][F >> 1]);
      GLDS16(V + (size_t)row * S_ + k0 + sin,    &Vs[b][F >> 1]);
    }
  };

  STAGE(0, 0);
  asm volatile("s_waitcnt vmcnt(0) lgkmcnt(0)" ::: "memory");
  __builtin_amdgcn_s_barrier();

  int cur = 0;
  for (int t = 0; t < NT; t++) {
    if (t + 1 < NT) STAGE(cur ^ 1, t + 1);
    unsigned long long mw = MaskL[t];
    uint32_t mlo = (uint32_t)mw, mhi = (uint32_t)(mw >> 32);

    // S^T = K Q^T : C[col=q=l16][row=key=nb*16+g*4+r]
    f32x4 sc[4];
    for (int nb = 0; nb < 4; nb++) sc[nb] = z;
    for (int nb = 0; nb < 4; nb++) {
      int rb = (nb * 16 + l16) * 64;
      for (int ks = 0; ks < 2; ks++) {
        bf16x8 kf = *(const bf16x8*)(&Ks[cur][rb + rof[ks]]);
        sc[nb] = MFMA16(kf, qf[ks], sc[nb]);
      }
    }

    // row max over ALL keys (masked included — ratio-exact; masked V rows are zero,
    // masked p excluded from l below)
    float m0 = max3f(sc[0][0], sc[0][1], sc[0][2]);
    float m1 = max3f(sc[0][3], sc[1][0], sc[1][1]);
    float m2 = max3f(sc[1][2], sc[1][3], sc[2][0]);
    float m3 = max3f(sc[2][1], sc[2][2], sc[2][3]);
    float m4 = max3f(sc[3][0], sc[3][1], sc[3][2]);
    float m5 = max3f(m0, m1, sc[3][3]);
    float m6 = max3f(m2, m3, m4);
    float pmax = fmaxf(m5, m6);
    pmax = fmaxf(pmax, __shfl_xor(pmax, 16, 64));
    pmax = fmaxf(pmax, __shfl_xor(pmax, 32, 64));

    // defer-max (THR = 8 log2-units, raw domain)
    if (__ballot(pmax > m_l + THRRAW)) {
      float mnew = fmaxf(m_l, pmax);
      float alpha = __builtin_amdgcn_exp2f((m_l - mnew) * SCL2);
      for (int db = 0; db < 4; db++) po[db] *= alpha;
      l_l *= alpha;
      m_l = mnew;
    }
    float negmsc = m_l * (-SCL2);

    // p = 2^(fma(s, SCL2, -m*SCL2)); l += p*b (b = mask bit); pack p pairs via cvt_pk
    float rsum = 0.f;
    bf16x4 pb[4];
    for (int nb = 0; nb < 4; nb++) {
      uint32_t msrc = (nb < 2) ? mlo : mhi;
      float pr[4];
      for (int r = 0; r < 4; r++) {
        float p = __builtin_amdgcn_exp2f(__builtin_fmaf(sc[nb][r], SCL2, negmsc));
        float b = (float)((msrc >> ((nb & 1) * 16 + g * 4 + r)) & 1u);
        rsum = __builtin_fmaf(p, b, rsum);
        pr[r] = p;
      }
      union { uint32_t w[2]; bf16x4 v; } pu;
      pu.w[0] = cvtpk(pr[0], pr[1]);
      pu.w[1] = cvtpk(pr[2], pr[3]);
      pb[nb] = pu.v;
    }
    rsum += __shfl_xor(rsum, 16, 64);
    rsum += __shfl_xor(rsum, 32, 64);
    l_l += rsum;

    // O^T += V^T P^T : A = Vs[d][key] b64 frags, B = pb (in-register)
    for (int db = 0; db < 4; db++) {
      int rb = (db * 16 + l16) * 64;
      for (int nb = 0; nb < 4; nb++) {
        bf16x4 va = *(const bf16x4*)(&Vs[cur][rb + vof[nb]]);
        po[db] = MFMA16K16(va, pb[nb], po[db]);
      }
    }

    asm volatile("s_waitcnt vmcnt(0) lgkmcnt(0)" ::: "memory");
    __builtin_amdgcn_s_barrier();
    cur ^= 1;
  }

  float inv = 1.0f / l_l;
  int q = q0 + w * 16 + l16;
  for (int db = 0; db < 4; db++) {
    f32x4 v = po[db] * inv;
    *(f32x4*)(out + (size_t)q * HID_ + h * 64 + db * 16 + g * 4) = v;
  }
}

extern "C" void kernel_launch(void* const* d_in, const int* in_sizes, int n_in,
                              void* d_out, int out_size, void* d_ws, size_t ws_size,
                              hipStream_t stream) {
  const float* x    = (const float*)d_in[0];
  const int*   mask = (const int*)d_in[1];
  const float* Wq   = (const float*)d_in[2];
  const float* bq   = (const float*)d_in[3];
  const float* Wk   = (const float*)d_in[4];
  const float* bk   = (const float*)d_in[5];
  const float* Wv   = (const float*)d_in[6];
  const float* bv   = (const float*)d_in[7];
  float* out = (float*)d_out;

  uint8_t* ws = (uint8_t*)d_ws;
  unsigned short* xb  = (unsigned short*)ws;                      // 8 MB (dead after GEMM)
  unsigned short* wt  = (unsigned short*)(ws + (8u  << 20));      // 6 MB (dead after GEMM)
  unsigned short* qkv = (unsigned short*)(ws + (14u << 20));      // 24 MB
  unsigned short* vt  = (unsigned short*)ws;                      // reuse xb slot: 8 MB
  unsigned long long* mb = (unsigned long long*)(ws + (8u << 20)); // reuse wt slot: 512 B

  cvt_x_kern<<<(S_ * HID_) / (256 * 4), 256, 0, stream>>>(x, xb);
  dim3 tg(HID_ / 32, HID_ / 32);
  cvt_w_t_kern<<<tg, dim3(32, 8), 0, stream>>>(Wq, wt, 0);
  cvt_w_t_kern<<<tg, dim3(32, 8), 0, stream>>>(Wk, wt, 1024);
  cvt_w_t_kern<<<tg, dim3(32, 8), 0, stream>>>(Wv, wt, 2048);
  gemm_qkv_kern<<<dim3(S_ / BM, N3 / BN), 256, 0, stream>>>(xb, wt, bq, bk, bv, qkv);
  vt_kern<<<dim3(S_ / 64, H_), 256, 0, stream>>>(qkv, mask, vt); // overwrites xb (dead)
  maskbits_kern<<<1, 64, 0, stream>>>(mask, mb);                 // overwrites wt (dead)
  attn_kern<<<S_ / 64 * H_, 256, 0, stream>>>(qkv, vt, mb, out);
}

// Round 12
// 255.550 us; speedup vs baseline: 1.8292x; 1.0243x over previous
//
#include <hip/hip_runtime.h>
#include <stdint.h>

#define S_    4096
#define HID_  1024
#define H_    16
#define N3    3072
#define NT    64
#define SCALE_f 0.125f
#define NEG_f  (-1e30f)
#define SCL2  (0.125f * 1.44269504089f)   // SCALE * log2(e)
#define THRRAW 44.3614f                   // 8 log2-units in raw-score domain

typedef __attribute__((ext_vector_type(4))) float f32x4;
typedef __attribute__((ext_vector_type(8))) short bf16x8;
typedef __attribute__((ext_vector_type(4))) short bf16x4;

#define MFMA16(a,b,c) __builtin_amdgcn_mfma_f32_16x16x32_bf16((a),(b),(c),0,0,0)
#define GLDS16(g,l) __builtin_amdgcn_global_load_lds( \
    (__attribute__((address_space(1))) void*)(g), \
    (__attribute__((address_space(3))) void*)(l), 16, 0, 0)

__device__ __forceinline__ f32x4 MFMA16K16(bf16x4 a, bf16x4 b, f32x4 c){
#if __has_builtin(__builtin_amdgcn_mfma_f32_16x16x16bf16_1k)
  return __builtin_amdgcn_mfma_f32_16x16x16bf16_1k(a, b, c, 0, 0, 0);
#else
  asm volatile("v_mfma_f32_16x16x16_bf16 %0, %1, %2, %0" : "+v"(c) : "v"(a), "v"(b));
  return c;
#endif
}

__device__ __forceinline__ float max3f(float a, float b, float c){
  float d; asm("v_max3_f32 %0, %1, %2, %3" : "=v"(d) : "v"(a), "v"(b), "v"(c)); return d;
}
__device__ __forceinline__ uint32_t cvtpk(float lo, float hi){
  uint32_t r; asm("v_cvt_pk_bf16_f32 %0, %1, %2" : "=v"(r) : "v"(lo), "v"(hi)); return r;
}

__device__ __forceinline__ unsigned short f2b(float f){
  union { float f; uint32_t u; } a; a.f = f;
  uint32_t u = a.u;
  return (unsigned short)((u + 0x7fffu + ((u >> 16) & 1u)) >> 16);
}

// ---------------- cast x -> bf16 ----------------
__global__ __launch_bounds__(256) void cvt_x_kern(const float* __restrict__ x,
                                                  unsigned short* __restrict__ xb){
  int i = (blockIdx.x * 256 + threadIdx.x) * 4;
  const float4 v = *(const float4*)(x + i);
  ushort4 o;
  o.x = f2b(v.x); o.y = f2b(v.y); o.z = f2b(v.z); o.w = f2b(v.w);
  *(ushort4*)(xb + i) = o;
}

// ------------- transpose+cast W[k][n] -> wt[n][k] bf16 -------------
__global__ __launch_bounds__(256) void cvt_w_t_kern(const float* __restrict__ W,
                                                    unsigned short* __restrict__ wt,
                                                    int nbase){
  __shared__ float tile[32][33];
  int k0 = blockIdx.x * 32, n0 = blockIdx.y * 32;
  int tx = threadIdx.x, ty = threadIdx.y;   // 32 x 8
  for (int i = 0; i < 32; i += 8)
    tile[ty + i][tx] = W[(k0 + ty + i) * HID_ + n0 + tx];
  __syncthreads();
  for (int i = 0; i < 32; i += 8)
    wt[(nbase + n0 + ty + i) * HID_ + k0 + tx] = f2b(tile[tx][ty + i]);
}

// ------------- fused QKV GEMM (m97 structure, unchanged) -------------
#define BM 128
#define BN 128
#define BK 32
__global__ __launch_bounds__(256) void gemm_qkv_kern(
    const unsigned short* __restrict__ xb,
    const unsigned short* __restrict__ wt,
    const float* __restrict__ bq, const float* __restrict__ bk,
    const float* __restrict__ bv,
    unsigned short* __restrict__ qkv)
{
  __shared__ unsigned short As[BM * BK];
  __shared__ unsigned short Bs[BN * BK];
  int tid = threadIdx.x;
  int lane = tid & 63, wid = tid >> 6;
  int g = lane >> 4, l16 = lane & 15;
  int m0 = blockIdx.x * BM, n0 = blockIdx.y * BN;
  int wm = (wid >> 1) * 64, wn = (wid & 1) * 64;

  f32x4 acc[4][4];
  f32x4 z = {0.f, 0.f, 0.f, 0.f};
  for (int mi = 0; mi < 4; mi++) for (int ni = 0; ni < 4; ni++) acc[mi][ni] = z;

  for (int kt = 0; kt < HID_; kt += BK) {
    __syncthreads();
    for (int i = 0; i < 2; i++) {
      int flat = tid * 8 + i * 2048;
      int m = flat >> 5, k = flat & 31;
      GLDS16(xb + (m0 + m) * HID_ + kt + k, As + flat);
    }
    for (int i = 0; i < 2; i++) {
      int flat = tid * 8 + i * 2048;
      int n = flat >> 5, k = flat & 31;
      GLDS16(wt + (n0 + n) * HID_ + kt + k, Bs + flat);
    }
    __syncthreads();
    bf16x8 a[4], b[4];
    for (int mi = 0; mi < 4; mi++)
      a[mi] = *(const bf16x8*)(As + (wm + mi * 16 + l16) * BK + g * 8);
    for (int ni = 0; ni < 4; ni++)
      b[ni] = *(const bf16x8*)(Bs + (wn + ni * 16 + l16) * BK + g * 8);
    for (int mi = 0; mi < 4; mi++)
      for (int ni = 0; ni < 4; ni++)
        acc[mi][ni] = MFMA16(a[mi], b[ni], acc[mi][ni]);
  }

  for (int mi = 0; mi < 4; mi++)
    for (int ni = 0; ni < 4; ni++) {
      int col = n0 + wn + ni * 16 + l16;
      float bias = (col < 1024) ? bq[col] : ((col < 2048) ? bk[col - 1024] : bv[col - 2048]);
      for (int r = 0; r < 4; r++) {
        int row = m0 + wm + mi * 16 + g * 4 + r;
        qkv[row * N3 + col] = f2b(acc[mi][ni][r] + bias);
      }
    }
}

// ------------- V transpose + mask-zeroing of BOTH K and V rows -------------
// vt[h][d][s] from qkv V region; masked keys: V row -> 0 (O unaffected) and
// K row -> 0 (score exactly 0, enables closed-form l correction).
__global__ __launch_bounds__(256) void vt_kern(unsigned short* __restrict__ qkv,
                                               const int* __restrict__ mask,
                                               unsigned short* __restrict__ vt){
  __shared__ unsigned short tl[64][72];
  int h = blockIdx.y, k0 = blockIdx.x * 64, tid = threadIdx.x;
  int key = tid >> 2, dq = (tid & 3) * 16;
  unsigned short* src = qkv + (size_t)(k0 + key) * N3 + 2048 + h * 64 + dq;
  bf16x8 v0 = *(const bf16x8*)src;
  bf16x8 v1 = *(const bf16x8*)(src + 8);
  if (mask[k0 + key] == 0) {
    bf16x8 zz = {0,0,0,0,0,0,0,0};
    v0 = zz; v1 = zz;
    unsigned short* kdst = qkv + (size_t)(k0 + key) * N3 + 1024 + h * 64 + dq;
    *(bf16x8*)kdst = zz; *(bf16x8*)(kdst + 8) = zz;   // zero K row slice too
  }
  *(bf16x8*)&tl[key][dq]     = v0;
  *(bf16x8*)&tl[key][dq + 8] = v1;
  __syncthreads();
  int d = tid >> 2, kq = (tid & 3) * 16;
  unsigned short* dst = vt + ((size_t)h * 64 + d) * S_ + k0 + kq;
  bf16x8 o0, o1;
  for (int j = 0; j < 8; j++) { o0[j] = tl[kq + j][d]; o1[j] = tl[kq + 8 + j][d]; }
  *(bf16x8*)dst = o0; *(bf16x8*)(dst + 8) = o1;
}

// ------------- mask -> per-64-key-tile MASKED count (float) -------------
__global__ void maskcnt_kern(const int* __restrict__ mask,
                             float* __restrict__ mc){
  int t = threadIdx.x;   // 64 threads
  int c = 0;
  for (int j = 0; j < 64; j++) c += (mask[t * 64 + j] == 0);
  mc[t] = (float)c;
}

// ------------- flash attention: QBLK=128 (2 q-groups/wave), closed-form mask-l -------------
__global__ __launch_bounds__(256, 2) void attn_kern(
    const unsigned short* __restrict__ qkv,
    const unsigned short* __restrict__ vt,   // [16][64][4096], masked rows zeroed
    const float* __restrict__ mc,            // [64] masked-count per key-tile
    float* __restrict__ out)
{
  __shared__ unsigned short Ks[2][64 * 64];   // [key][dim], XOR-swizzled
  __shared__ unsigned short Vs[2][64 * 64];   // [d][key],  XOR-swizzled
  __shared__ float MaskC[NT];

  int tid = threadIdx.x, lane = tid & 63, w = tid >> 6;
  int g = lane >> 4, l16 = lane & 15;
  int bid = blockIdx.x;
  int swz = (bid & 7) * 64 + (bid >> 3);      // XCD swizzle (512 = 8 x 64, bijective)
  int h = swz >> 5, q0 = (swz & 31) * 128;

  const unsigned short* Q = qkv + h * 64;
  const unsigned short* K = qkv + 1024 + h * 64;
  const unsigned short* V = vt + (size_t)h * 64 * S_;

  if (tid < NT) MaskC[tid] = mc[tid];

  // Q fragments: wave w owns q-rows q0 + w*32 + j*16 + l16, j = 0,1
  bf16x8 qf[2][2];
  for (int j = 0; j < 2; j++)
    for (int ks = 0; ks < 2; ks++)
      qf[j][ks] = *(const bf16x8*)(Q + (size_t)(q0 + w * 32 + j * 16 + l16) * N3 + ks * 32 + g * 8);

  f32x4 po[2][4];
  f32x4 z = {0.f, 0.f, 0.f, 0.f};
  for (int j = 0; j < 2; j++) for (int db = 0; db < 4; db++) po[j][db] = z;
  float m_l[2] = {-__builtin_inff(), -__builtin_inff()};
  float l_l[2] = {0.f, 0.f};

  int swl = (l16 & 7) << 4;
  int rof[2];
  for (int ks = 0; ks < 2; ks++) rof[ks] = ((ks * 64 + g * 16) ^ swl) >> 1;
  int vof[4];
  for (int nb = 0; nb < 4; nb++) vof[nb] = ((nb * 32 + g * 8) ^ swl) >> 1;

  auto STAGE = [&](int b, int t) {
    int k0 = t * 64;
    for (int i = 0; i < 2; i++) {
      int F = tid * 16 + i * 4096;
      int row = F >> 7, inner = F & 127;
      int sin = (inner ^ ((row & 7) << 4)) >> 1;
      GLDS16(K + (size_t)(k0 + row) * N3 + sin, &Ks[b][F >> 1]);
      GLDS16(V + (size_t)row * S_ + k0 + sin,    &Vs[b][F >> 1]);
    }
  };

  STAGE(0, 0);
  asm volatile("s_waitcnt vmcnt(0) lgkmcnt(0)" ::: "memory");
  __builtin_amdgcn_s_barrier();

  int cur = 0;
  for (int t = 0; t < NT; t++) {
    if (t + 1 < NT) STAGE(cur ^ 1, t + 1);
    float cf = MaskC[t];

    bf16x4 pb[2][4];
    for (int j = 0; j < 2; j++) {
      // S^T = K Q^T : C[col=q=l16][row=key=nb*16+g*4+r]; masked keys give s = 0 exactly
      f32x4 sc[4];
      for (int nb = 0; nb < 4; nb++) sc[nb] = z;
      for (int nb = 0; nb < 4; nb++) {
        int rb = (nb * 16 + l16) * 64;
        for (int ks = 0; ks < 2; ks++) {
          bf16x8 kf = *(const bf16x8*)(&Ks[cur][rb + rof[ks]]);
          sc[nb] = MFMA16(kf, qf[j][ks], sc[nb]);
        }
      }

      // row max (raw domain; masked zeros included — ratio-exact)
      float m0 = max3f(sc[0][0], sc[0][1], sc[0][2]);
      float m1 = max3f(sc[0][3], sc[1][0], sc[1][1]);
      float m2 = max3f(sc[1][2], sc[1][3], sc[2][0]);
      float m3 = max3f(sc[2][1], sc[2][2], sc[2][3]);
      float m4 = max3f(sc[3][0], sc[3][1], sc[3][2]);
      float m5 = max3f(m0, m1, sc[3][3]);
      float m6 = max3f(m2, m3, m4);
      float pmax = fmaxf(m5, m6);
      pmax = fmaxf(pmax, __shfl_xor(pmax, 16, 64));
      pmax = fmaxf(pmax, __shfl_xor(pmax, 32, 64));

      if (__ballot(pmax > m_l[j] + THRRAW)) {
        float mnew = fmaxf(m_l[j], pmax);
        float alpha = __builtin_amdgcn_exp2f((m_l[j] - mnew) * SCL2);
        for (int db = 0; db < 4; db++) po[j][db] *= alpha;
        l_l[j] *= alpha;
        m_l[j] = mnew;
      }
      float negmsc = m_l[j] * (-SCL2);

      // p = 2^(fma(s, SCL2, -m*SCL2)); masked keys contribute exactly p0 = 2^(-m*SCL2)
      float rsum = 0.f;
      for (int nb = 0; nb < 4; nb++) {
        float pr[4];
        for (int r = 0; r < 4; r++) {
          float p = __builtin_amdgcn_exp2f(__builtin_fmaf(sc[nb][r], SCL2, negmsc));
          rsum += p;
          pr[r] = p;
        }
        union { uint32_t wd[2]; bf16x4 v; } pu;
        pu.wd[0] = cvtpk(pr[0], pr[1]);
        pu.wd[1] = cvtpk(pr[2], pr[3]);
        pb[j][nb] = pu.v;
      }
      rsum += __shfl_xor(rsum, 16, 64);
      rsum += __shfl_xor(rsum, 32, 64);
      float p0 = __builtin_amdgcn_exp2f(negmsc);
      l_l[j] += __builtin_fmaf(-cf, p0, rsum);   // subtract masked contributions
    }

    // O^T += V^T P^T : each va read feeds BOTH q-groups (LDS-per-q halved)
    for (int db = 0; db < 4; db++) {
      int rb = (db * 16 + l16) * 64;
      for (int nb = 0; nb < 4; nb++) {
        bf16x4 va = *(const bf16x4*)(&Vs[cur][rb + vof[nb]]);
        po[0][db] = MFMA16K16(va, pb[0][nb], po[0][db]);
        po[1][db] = MFMA16K16(va, pb[1][nb], po[1][db]);
      }
    }

    asm volatile("s_waitcnt vmcnt(0) lgkmcnt(0)" ::: "memory");
    __builtin_amdgcn_s_barrier();
    cur ^= 1;
  }

  for (int j = 0; j < 2; j++) {
    float inv = 1.0f / l_l[j];
    int q = q0 + w * 32 + j * 16 + l16;
    for (int db = 0; db < 4; db++) {
      f32x4 v = po[j][db] * inv;
      *(f32x4*)(out + (size_t)q * HID_ + h * 64 + db * 16 + g * 4) = v;
    }
  }
}

extern "C" void kernel_launch(void* const* d_in, const int* in_sizes, int n_in,
                              void* d_out, int out_size, void* d_ws, size_t ws_size,
                              hipStream_t stream) {
  const float* x    = (const float*)d_in[0];
  const int*   mask = (const int*)d_in[1];
  const float* Wq   = (const float*)d_in[2];
  const float* bq   = (const float*)d_in[3];
  const float* Wk   = (const float*)d_in[4];
  const float* bk   = (const float*)d_in[5];
  const float* Wv   = (const float*)d_in[6];
  const float* bv   = (const float*)d_in[7];
  float* out = (float*)d_out;

  uint8_t* ws = (uint8_t*)d_ws;
  unsigned short* xb  = (unsigned short*)ws;                      // 8 MB (dead after GEMM)
  unsigned short* wt  = (unsigned short*)(ws + (8u  << 20));      // 6 MB (dead after GEMM)
  unsigned short* qkv = (unsigned short*)(ws + (14u << 20));      // 24 MB
  unsigned short* vt  = (unsigned short*)ws;                      // reuse xb slot: 8 MB
  float* mc = (float*)(ws + (8u << 20));                          // reuse wt slot: 256 B

  cvt_x_kern<<<(S_ * HID_) / (256 * 4), 256, 0, stream>>>(x, xb);
  dim3 tg(HID_ / 32, HID_ / 32);
  cvt_w_t_kern<<<tg, dim3(32, 8), 0, stream>>>(Wq, wt, 0);
  cvt_w_t_kern<<<tg, dim3(32, 8), 0, stream>>>(Wk, wt, 1024);
  cvt_w_t_kern<<<tg, dim3(32, 8), 0, stream>>>(Wv, wt, 2048);
  gemm_qkv_kern<<<dim3(S_ / BM, N3 / BN), 256, 0, stream>>>(xb, wt, bq, bk, bv, qkv);
  vt_kern<<<dim3(S_ / 64, H_), 256, 0, stream>>>(qkv, mask, vt); // overwrites xb (dead)
  maskcnt_kern<<<1, 64, 0, stream>>>(mask, mc);                  // overwrites wt (dead)
  attn_kern<<<(S_ / 128) * H_, 256, 0, stream>>>(qkv, vt, mc, out);
}